// Round 9
// baseline (227.813 us; speedup 1.0000x reference)
//
#include <hip/hip_runtime.h>

#define TT 8192
#define DD 512
#define NN 4
#define JS 16
#define JR (TT / JS)        // 512 columns per slice
#define BIGU 0xFFFFFFFFu

typedef unsigned int uint;
typedef unsigned short ushort;
typedef __attribute__((ext_vector_type(4))) int int4v;      // 4 VGPRs (16 i8)
typedef __attribute__((ext_vector_type(4))) float f32x4;

// fused: int8 quantize (x16, RTN) + row sum-of-squares (exact int)
__global__ void cvtq8_kernel(const float* __restrict__ X, uint2* __restrict__ Xb,
                             int* __restrict__ sqq) {
  int w = threadIdx.x >> 6, l = threadIdx.x & 63;
  int row = blockIdx.x * 4 + w;
  const float4* xr = (const float4*)(X + (size_t)row * DD) + l * 2;
  float4 a = xr[0], b = xr[1];
  int q[8];
  q[0] = __float2int_rn(a.x * 16.f); q[1] = __float2int_rn(a.y * 16.f);
  q[2] = __float2int_rn(a.z * 16.f); q[3] = __float2int_rn(a.w * 16.f);
  q[4] = __float2int_rn(b.x * 16.f); q[5] = __float2int_rn(b.y * 16.f);
  q[6] = __float2int_rn(b.z * 16.f); q[7] = __float2int_rn(b.w * 16.f);
  int s = 0;
#pragma unroll
  for (int i = 0; i < 8; ++i) {
    q[i] = max(-127, min(127, q[i]));
    s += q[i] * q[i];
  }
  uint2 o;
  o.x = (uint)(q[0] & 255) | ((uint)(q[1] & 255) << 8) |
        ((uint)(q[2] & 255) << 16) | ((uint)(q[3] & 255) << 24);
  o.y = (uint)(q[4] & 255) | ((uint)(q[5] & 255) << 8) |
        ((uint)(q[6] & 255) << 16) | ((uint)(q[7] & 255) << 24);
  Xb[(size_t)row * 64 + l] = o;
#pragma unroll
  for (int off = 32; off >= 1; off >>= 1) s += __shfl_down(s, off, 64);
  if (l == 0) sqq[row] = s;
}

// global->LDS async 16B
__device__ __forceinline__ void gload16(const void* g, void* l) {
  __builtin_amdgcn_global_load_lds(
      (const __attribute__((address_space(1))) void*)(size_t)g,
      (__attribute__((address_space(3))) void*)(uint)(size_t)l, 16, 0, 0);
}

// 3-term XOR swizzle: row r (64B = 4x16B chunks), slot s holds source chunk s^g(r).
__device__ __forceinline__ int swz(int r) {
  return (r & 3) ^ ((r >> 1) & 2) ^ ((r >> 3) & 1);
}

// i8-MFMA distance GEMM (transposed: m=j, n=i), 128x128 tile, BK=64,
// 32 stages, double-buffered LDS (2x16KB), split-barrier counted-vmcnt
// pipeline, exact-integer key selection. (Byte-identical to round 8.)
__global__ __launch_bounds__(256, 4) void gemm_topk(
    const char* __restrict__ Xb, const int* __restrict__ sqq,
    uint* __restrict__ ckey) {
  __shared__ char smem[32768];        // 2 stage buffers; merge overlays

  const int t = threadIdx.x;
  const int w = t >> 6, l = t & 63;
  const int l15 = l & 15, q4 = l >> 4;
  // XCD-bijective swizzle: each XCD owns 8 i-panels (all 16 slices).
  const int bid = (blockIdx.x & 7) * 128 + (blockIdx.x >> 3);
  const int bi = bid >> 4;            // 64 row-blocks of 128 i-rows
  const int bs = bid & 15;            // 16 j-slices
  const int i0 = bi * 128;
  const int js0 = bs * JR;
  const int mq = (w & 1) * 64;        // wave's j-quadrant
  const int nq = (w >> 1) * 64;       // wave's i-quadrant

  const char* gQ[4];
#pragma unroll
  for (int q = 0; q < 4; ++q) {
    int cidx = q * 256 + t;
    int r = cidx >> 2, slot = cidx & 3;
    int cs = slot ^ swz(r);
    int rowg = (r < 128) ? (i0 + r) : (js0 + r - 128);
    gQ[q] = Xb + (size_t)rowg * 512 + cs * 16;
  }

  // loop-invariant: sqq for this lane's 4 i-columns
  int si[4];
#pragma unroll
  for (int cb = 0; cb < 4; ++cb) si[cb] = sqq[i0 + nq + cb * 16 + l15];

  uint L[4][4];                       // per-(lane, i-frag) top-4 packed keys
#pragma unroll
  for (int cb = 0; cb < 4; ++cb)
#pragma unroll
    for (int s = 0; s < 4; ++s) L[cb][s] = BIGU;

  int4v acc[4][4];
#pragma unroll
  for (int rb = 0; rb < 4; ++rb)
#pragma unroll
    for (int cb = 0; cb < 4; ++cb) {
      int4v z = {0, 0, 0, 0};
      acc[rb][cb] = z;
    }

  {  // prologue: DMA stage 0 into buf0
#pragma unroll
    for (int q = 0; q < 4; ++q)
      gload16(gQ[q], smem + (q * 256 + t) * 16);
  }
  asm volatile("" ::: "memory");

  int cellA[4], cellB[4];
#pragma unroll
  for (int rb = 0; rb < 4; ++rb) {
    int rj = 128 + mq + rb * 16 + l15;
    cellA[rb] = rj * 4 + (q4 ^ swz(rj));
  }
#pragma unroll
  for (int cb = 0; cb < 4; ++cb) {
    int ri = nq + cb * 16 + l15;
    cellB[cb] = ri * 4 + (q4 ^ swz(ri));
  }

  for (int s = 0; s < 32; ++s) {      // 4 j-tiles x 8 k-stages, linearized
    const int kt = s & 7, jt = s >> 3;

    // B1: all waves finished compute(s-1) -> safe to overwrite buf[(s+1)&1]
    __builtin_amdgcn_s_barrier();
    asm volatile("" ::: "memory");

    {  // issue prefetch stage s+1 into the other buffer (wraps at s=31)
      const int sn = (s + 1) & 31;
      const int ioff = (sn & 7) * 64;
      const int joff = ioff + (sn >> 3) * 65536;   // j-tile: 128 rows x 512 B
      char* dbase = smem + ((s + 1) & 1) * 16384;
#pragma unroll
      for (int q = 0; q < 4; ++q)
        gload16(gQ[q] + (q < 2 ? ioff : joff), dbase + (q * 256 + t) * 16);
    }

    // wait for MY stage-s loads (oldest 4); stage-(s+1) loads stay in flight
    asm volatile("s_waitcnt vmcnt(4)" ::: "memory");
    // B2: everyone's stage-s DMA has landed
    __builtin_amdgcn_s_barrier();
    asm volatile("" ::: "memory");

    {  // compute stage s: one 16x16x64 i8 k-step
      const char* base = smem + (s & 1) * 16384;
      int4v af[4], bf[4];
#pragma unroll
      for (int rb = 0; rb < 4; ++rb)
        af[rb] = *(const int4v*)(base + cellA[rb] * 16);
#pragma unroll
      for (int cb = 0; cb < 4; ++cb)
        bf[cb] = *(const int4v*)(base + cellB[cb] * 16);
#pragma unroll
      for (int rb = 0; rb < 4; ++rb)
#pragma unroll
        for (int cb = 0; cb < 4; ++cb)
          acc[rb][cb] = __builtin_amdgcn_mfma_i32_16x16x64_i8(
              af[rb], bf[cb], acc[rb][cb], 0, 0, 0);
    }

    if (kt == 7) {                    // per-j-tile selection epilogue
      const int jb = js0 + jt * 128;
      // D layout: col(lane&15)=i-local, row(q4*4+reg)=j-local
#pragma unroll
      for (int rb = 0; rb < 4; ++rb) {
        int jg = jb + mq + rb * 16 + q4 * 4;
        int4 sj = *(const int4*)(sqq + jg);
        int s4[4] = {sj.x, sj.y, sj.z, sj.w};
#pragma unroll
        for (int cb = 0; cb < 4; ++cb) {
#pragma unroll
          for (int r = 0; r < 4; ++r) {
            int kint = s4[r] + si[cb] - 2 * acc[rb][cb][r];  // exact d^2_q >= 0
            uint ku = (uint)kint;
            if (ku > 0x7FFFFu) ku = 0x7FFFFu;                // 19-bit guard
            uint p = (ku << 13) | (uint)(jg + r);            // 19b key | 13b j
            if (p < L[cb][3]) {
              L[cb][3] = p;
#pragma unroll
              for (int x = 3; x >= 1; --x) {
                uint lo = L[cb][x - 1], hi = L[cb][x];
                bool sw = hi < lo;
                L[cb][x - 1] = sw ? hi : lo;
                L[cb][x] = sw ? lo : hi;
              }
            }
          }
        }
      }
      // re-zero accumulators for next j-tile
#pragma unroll
      for (int rb = 0; rb < 4; ++rb)
#pragma unroll
        for (int cb = 0; cb < 4; ++cb) {
          int4v z = {0, 0, 0, 0};
          acc[rb][cb] = z;
        }
    }
  }

  // drain wrap DMA before overlaying LDS with the merge buffer
  asm volatile("s_waitcnt vmcnt(0)" ::: "memory");
  __builtin_amdgcn_s_barrier();
  asm volatile("" ::: "memory");

  uint* ml = (uint*)smem;              // [128 rows][33]
  const int cid = (w & 1) * 4 + q4;    // 8 contributors per row
#pragma unroll
  for (int cb = 0; cb < 4; ++cb) {
    int n = nq + cb * 16 + l15;
#pragma unroll
    for (int s = 0; s < 4; ++s) ml[n * 33 + cid * 4 + s] = L[cb][s];
  }
  __syncthreads();
  if (t < 128) {
    uint best[8];
#pragma unroll
    for (int s = 0; s < 8; ++s) best[s] = BIGU;
    for (int u = 0; u < 32; ++u) {
      uint p = ml[t * 33 + u];
      if (p < best[7]) {
        best[7] = p;
#pragma unroll
        for (int s = 7; s >= 1; --s) {
          uint lo = best[s - 1], hi = best[s];
          bool sw = hi < lo;
          best[s - 1] = sw ? hi : lo;
          best[s] = sw ? lo : hi;
        }
      }
    }
#pragma unroll
    for (int s = 0; s < 8; ++s)
      ckey[(size_t)(i0 + t) * 128 + bs * 8 + s] = best[s];
  }
}

// refine v4: rank-count top-16 of 128, group-parallel f32 re-rank AND
// group-parallel RANKING (each 4-lane group ranks its own candidate via
// 4 shfl + count; rank->index scatter to LDS; targets = direct LDS lookup).
// Removes the O(16^2) rank loop, 16 shfl broadcasts, and 3x16-reg arrays.
__global__ __launch_bounds__(256, 8) void refine_gen(
    const float* __restrict__ X, const uint* __restrict__ ckey,
    const float* __restrict__ gaps, const int* __restrict__ nnc,
    float* __restrict__ out) {
  __shared__ uint keys[4][128];
  __shared__ uint seln[4][16];
  __shared__ uint srank[4][16];       // rank -> neighbor index
  __shared__ float xs[4][512];        // own-row stash (broadcast reads)
  const int w = threadIdx.x >> 6, l = threadIdx.x & 63;
  const int row = blockIdx.x * 4 + w;

  uint k0 = ckey[(size_t)row * 128 + l];
  uint k1 = ckey[(size_t)row * 128 + 64 + l];
  keys[w][l] = k0;
  keys[w][64 + l] = k1;

  // own-row fragment (lane owns floats [8l, 8l+8)) — also stashed to LDS
  const float4* xr = (const float4*)(X + (size_t)row * DD) + l * 2;
  float4 xa = xr[0], xb = xr[1];
  float4* xsp = (float4*)xs[w];
  xsp[l * 2] = xa;
  xsp[l * 2 + 1] = xb;

  __syncthreads();

  // exact rank of each key among the 128 (keys unique by j-bits) -> top-16
  int r0 = 0, r1 = 0;
  const uint4* kk = (const uint4*)keys[w];
#pragma unroll
  for (int i = 0; i < 32; ++i) {
    uint4 v = kk[i];
    r0 += (v.x < k0) + (v.y < k0) + (v.z < k0) + (v.w < k0);
    r1 += (v.x < k1) + (v.y < k1) + (v.z < k1) + (v.w < k1);
  }
  if (r0 < 16) seln[w][r0] = k0 & 8191u;
  if (r1 < 16) seln[w][r1] = k1 & 8191u;
  __syncthreads();

  // group-parallel f32 distance: group g (lanes 4g..4g+3) -> candidate g.
  const int q = l & 3, g = l >> 2;
  const int jg = (int)seln[w][g];
  const float* yrow = X + (size_t)jg * DD;
  const float4* xls = (const float4*)xs[w];
  float a = 0.f;
#pragma unroll
  for (int k = 0; k < 32; ++k) {
    float4 y4 = ((const float4*)yrow)[k * 4 + q];
    float4 x4 = xls[k * 4 + q];
    float d0 = x4.x - y4.x;
    float d1 = x4.y - y4.y;
    float d2 = x4.z - y4.z;
    float d3 = x4.w - y4.w;
    a = fmaf(d0, d0, a);
    a = fmaf(d1, d1, a);
    a = fmaf(d2, d2, a);
    a = fmaf(d3, d3, a);
  }
  // xor-reduce within the 4-lane group: all 4 lanes hold d_g
  a += __shfl_xor(a, 1);
  a += __shfl_xor(a, 2);

  // group-parallel rank: lane q handles opponents u = 4q..4q+3
  int cnt = 0;
#pragma unroll
  for (int uu = 0; uu < 4; ++uu) {
    int u = q * 4 + uu;
    float du = __shfl(a, u * 4, 64);       // group u's sum (lane 4u holds it)
    int ju = (int)seln[w][u];
    cnt += (du < a || (du == a && ju < jg)) ? 1 : 0;  // self-pair adds 0
  }
  cnt += __shfl_xor(cnt, 1);
  cnt += __shfl_xor(cnt, 2);               // cnt = rank of candidate g
  if (q == 0) srank[w][cnt] = (uint)jg;    // ranks are a permutation: no clash
  __syncthreads();

  // targets are ranks 1..4 (rank 0 = self): direct lookup, then gather+interp
  int jsel[4];
  float gv[4];
#pragma unroll
  for (int o = 0; o < 4; ++o) {
    gv[o] = gaps[row * 4 + o];
    int target = nnc[row * 4 + o] + 1;     // skip self (rank 0)
    jsel[o] = (int)srank[w][target];
  }

#pragma unroll
  for (int o = 0; o < 4; ++o) {
    const float4* yr = (const float4*)(X + (size_t)jsel[o] * DD) + l * 2;
    float4 ya = yr[0], yb = yr[1];
    float gp = gv[o];
    f32x4 r0v, r1v;
    r0v.x = fmaf(gp, ya.x - xa.x, xa.x);
    r0v.y = fmaf(gp, ya.y - xa.y, xa.y);
    r0v.z = fmaf(gp, ya.z - xa.z, xa.z);
    r0v.w = fmaf(gp, ya.w - xa.w, xa.w);
    r1v.x = fmaf(gp, yb.x - xb.x, xb.x);
    r1v.y = fmaf(gp, yb.y - xb.y, xb.y);
    r1v.z = fmaf(gp, yb.z - xb.z, xb.z);
    r1v.w = fmaf(gp, yb.w - xb.w, xb.w);
    f32x4* dst = (f32x4*)(out + ((size_t)row * 4 + o) * DD) + l * 2;
    __builtin_nontemporal_store(r0v, dst);
    __builtin_nontemporal_store(r1v, dst + 1);
  }
}

extern "C" void kernel_launch(void* const* d_in, const int* in_sizes, int n_in,
                              void* d_out, int out_size, void* d_ws, size_t ws_size,
                              hipStream_t stream) {
  const float* X = (const float*)d_in[0];
  const float* gaps = (const float*)d_in[1];
  const int* nnc = (const int*)d_in[2];
  float* out = (float*)d_out;

  int* sqq = (int*)d_ws;                                      // 32 KB
  uint2* Xb8 = (uint2*)((char*)d_ws + 32768);                 // 4 MB i8 X
  uint* ckey = (uint*)((char*)d_ws + 32768 + 4194304);        // 4 MB candidates

  cvtq8_kernel<<<TT / 4, 256, 0, stream>>>(X, Xb8, sqq);
  gemm_topk<<<1024, 256, 0, stream>>>((const char*)Xb8, sqq, ckey);
  refine_gen<<<TT / 4, 256, 0, stream>>>(X, ckey, gaps, nnc, out);
}

// Round 10
// 171.571 us; speedup vs baseline: 1.3278x; 1.3278x over previous
//
#include <hip/hip_runtime.h>

#define TT 8192
#define DD 512
#define NN 4
#define JS 16
#define JR (TT / JS)        // 512 columns per slice
#define BIGU 0xFFFFFFFFu

typedef unsigned int uint;
typedef unsigned short ushort;
typedef __attribute__((ext_vector_type(4))) int int4v;      // 4 VGPRs (16 i8)
typedef __attribute__((ext_vector_type(4))) float f32x4;

// fused: int8 quantize (x16, RTN) + row sum-of-squares (exact int)
__global__ void cvtq8_kernel(const float* __restrict__ X, uint2* __restrict__ Xb,
                             int* __restrict__ sqq) {
  int w = threadIdx.x >> 6, l = threadIdx.x & 63;
  int row = blockIdx.x * 4 + w;
  const float4* xr = (const float4*)(X + (size_t)row * DD) + l * 2;
  float4 a = xr[0], b = xr[1];
  int q[8];
  q[0] = __float2int_rn(a.x * 16.f); q[1] = __float2int_rn(a.y * 16.f);
  q[2] = __float2int_rn(a.z * 16.f); q[3] = __float2int_rn(a.w * 16.f);
  q[4] = __float2int_rn(b.x * 16.f); q[5] = __float2int_rn(b.y * 16.f);
  q[6] = __float2int_rn(b.z * 16.f); q[7] = __float2int_rn(b.w * 16.f);
  int s = 0;
#pragma unroll
  for (int i = 0; i < 8; ++i) {
    q[i] = max(-127, min(127, q[i]));
    s += q[i] * q[i];
  }
  uint2 o;
  o.x = (uint)(q[0] & 255) | ((uint)(q[1] & 255) << 8) |
        ((uint)(q[2] & 255) << 16) | ((uint)(q[3] & 255) << 24);
  o.y = (uint)(q[4] & 255) | ((uint)(q[5] & 255) << 8) |
        ((uint)(q[6] & 255) << 16) | ((uint)(q[7] & 255) << 24);
  Xb[(size_t)row * 64 + l] = o;
#pragma unroll
  for (int off = 32; off >= 1; off >>= 1) s += __shfl_down(s, off, 64);
  if (l == 0) sqq[row] = s;
}

// global->LDS async 16B
__device__ __forceinline__ void gload16(const void* g, void* l) {
  __builtin_amdgcn_global_load_lds(
      (const __attribute__((address_space(1))) void*)(size_t)g,
      (__attribute__((address_space(3))) void*)(uint)(size_t)l, 16, 0, 0);
}

// 3-term XOR swizzle: row r (64B = 4x16B chunks), slot s holds source chunk s^g(r).
__device__ __forceinline__ int swz(int r) {
  return (r & 3) ^ ((r >> 1) & 2) ^ ((r >> 3) & 1);
}

// i8-MFMA distance GEMM (transposed: m=j, n=i), 128x128 tile, BK=64,
// 32 stages, double-buffered LDS (2x16KB), split-barrier counted-vmcnt
// pipeline, exact-integer key selection. (Byte-identical to rounds 8/9.)
__global__ __launch_bounds__(256, 4) void gemm_topk(
    const char* __restrict__ Xb, const int* __restrict__ sqq,
    uint* __restrict__ ckey) {
  __shared__ char smem[32768];        // 2 stage buffers; merge overlays

  const int t = threadIdx.x;
  const int w = t >> 6, l = t & 63;
  const int l15 = l & 15, q4 = l >> 4;
  // XCD-bijective swizzle: each XCD owns 8 i-panels (all 16 slices).
  const int bid = (blockIdx.x & 7) * 128 + (blockIdx.x >> 3);
  const int bi = bid >> 4;            // 64 row-blocks of 128 i-rows
  const int bs = bid & 15;            // 16 j-slices
  const int i0 = bi * 128;
  const int js0 = bs * JR;
  const int mq = (w & 1) * 64;        // wave's j-quadrant
  const int nq = (w >> 1) * 64;       // wave's i-quadrant

  const char* gQ[4];
#pragma unroll
  for (int q = 0; q < 4; ++q) {
    int cidx = q * 256 + t;
    int r = cidx >> 2, slot = cidx & 3;
    int cs = slot ^ swz(r);
    int rowg = (r < 128) ? (i0 + r) : (js0 + r - 128);
    gQ[q] = Xb + (size_t)rowg * 512 + cs * 16;
  }

  // loop-invariant: sqq for this lane's 4 i-columns
  int si[4];
#pragma unroll
  for (int cb = 0; cb < 4; ++cb) si[cb] = sqq[i0 + nq + cb * 16 + l15];

  uint L[4][4];                       // per-(lane, i-frag) top-4 packed keys
#pragma unroll
  for (int cb = 0; cb < 4; ++cb)
#pragma unroll
    for (int s = 0; s < 4; ++s) L[cb][s] = BIGU;

  int4v acc[4][4];
#pragma unroll
  for (int rb = 0; rb < 4; ++rb)
#pragma unroll
    for (int cb = 0; cb < 4; ++cb) {
      int4v z = {0, 0, 0, 0};
      acc[rb][cb] = z;
    }

  {  // prologue: DMA stage 0 into buf0
#pragma unroll
    for (int q = 0; q < 4; ++q)
      gload16(gQ[q], smem + (q * 256 + t) * 16);
  }
  asm volatile("" ::: "memory");

  int cellA[4], cellB[4];
#pragma unroll
  for (int rb = 0; rb < 4; ++rb) {
    int rj = 128 + mq + rb * 16 + l15;
    cellA[rb] = rj * 4 + (q4 ^ swz(rj));
  }
#pragma unroll
  for (int cb = 0; cb < 4; ++cb) {
    int ri = nq + cb * 16 + l15;
    cellB[cb] = ri * 4 + (q4 ^ swz(ri));
  }

  for (int s = 0; s < 32; ++s) {      // 4 j-tiles x 8 k-stages, linearized
    const int kt = s & 7, jt = s >> 3;

    // B1: all waves finished compute(s-1) -> safe to overwrite buf[(s+1)&1]
    __builtin_amdgcn_s_barrier();
    asm volatile("" ::: "memory");

    {  // issue prefetch stage s+1 into the other buffer (wraps at s=31)
      const int sn = (s + 1) & 31;
      const int ioff = (sn & 7) * 64;
      const int joff = ioff + (sn >> 3) * 65536;   // j-tile: 128 rows x 512 B
      char* dbase = smem + ((s + 1) & 1) * 16384;
#pragma unroll
      for (int q = 0; q < 4; ++q)
        gload16(gQ[q] + (q < 2 ? ioff : joff), dbase + (q * 256 + t) * 16);
    }

    // wait for MY stage-s loads (oldest 4); stage-(s+1) loads stay in flight
    asm volatile("s_waitcnt vmcnt(4)" ::: "memory");
    // B2: everyone's stage-s DMA has landed
    __builtin_amdgcn_s_barrier();
    asm volatile("" ::: "memory");

    {  // compute stage s: one 16x16x64 i8 k-step
      const char* base = smem + (s & 1) * 16384;
      int4v af[4], bf[4];
#pragma unroll
      for (int rb = 0; rb < 4; ++rb)
        af[rb] = *(const int4v*)(base + cellA[rb] * 16);
#pragma unroll
      for (int cb = 0; cb < 4; ++cb)
        bf[cb] = *(const int4v*)(base + cellB[cb] * 16);
#pragma unroll
      for (int rb = 0; rb < 4; ++rb)
#pragma unroll
        for (int cb = 0; cb < 4; ++cb)
          acc[rb][cb] = __builtin_amdgcn_mfma_i32_16x16x64_i8(
              af[rb], bf[cb], acc[rb][cb], 0, 0, 0);
    }

    if (kt == 7) {                    // per-j-tile selection epilogue
      const int jb = js0 + jt * 128;
      // D layout: col(lane&15)=i-local, row(q4*4+reg)=j-local
#pragma unroll
      for (int rb = 0; rb < 4; ++rb) {
        int jg = jb + mq + rb * 16 + q4 * 4;
        int4 sj = *(const int4*)(sqq + jg);
        int s4[4] = {sj.x, sj.y, sj.z, sj.w};
#pragma unroll
        for (int cb = 0; cb < 4; ++cb) {
#pragma unroll
          for (int r = 0; r < 4; ++r) {
            int kint = s4[r] + si[cb] - 2 * acc[rb][cb][r];  // exact d^2_q >= 0
            uint ku = (uint)kint;
            if (ku > 0x7FFFFu) ku = 0x7FFFFu;                // 19-bit guard
            uint p = (ku << 13) | (uint)(jg + r);            // 19b key | 13b j
            if (p < L[cb][3]) {
              L[cb][3] = p;
#pragma unroll
              for (int x = 3; x >= 1; --x) {
                uint lo = L[cb][x - 1], hi = L[cb][x];
                bool sw = hi < lo;
                L[cb][x - 1] = sw ? hi : lo;
                L[cb][x] = sw ? lo : hi;
              }
            }
          }
        }
      }
      // re-zero accumulators for next j-tile
#pragma unroll
      for (int rb = 0; rb < 4; ++rb)
#pragma unroll
        for (int cb = 0; cb < 4; ++cb) {
          int4v z = {0, 0, 0, 0};
          acc[rb][cb] = z;
        }
    }
  }

  // drain wrap DMA before overlaying LDS with the merge buffer
  asm volatile("s_waitcnt vmcnt(0)" ::: "memory");
  __builtin_amdgcn_s_barrier();
  asm volatile("" ::: "memory");

  uint* ml = (uint*)smem;              // [128 rows][33]
  const int cid = (w & 1) * 4 + q4;    // 8 contributors per row
#pragma unroll
  for (int cb = 0; cb < 4; ++cb) {
    int n = nq + cb * 16 + l15;
#pragma unroll
    for (int s = 0; s < 4; ++s) ml[n * 33 + cid * 4 + s] = L[cb][s];
  }
  __syncthreads();
  if (t < 128) {
    uint best[8];
#pragma unroll
    for (int s = 0; s < 8; ++s) best[s] = BIGU;
    for (int u = 0; u < 32; ++u) {
      uint p = ml[t * 33 + u];
      if (p < best[7]) {
        best[7] = p;
#pragma unroll
        for (int s = 7; s >= 1; --s) {
          uint lo = best[s - 1], hi = best[s];
          bool sw = hi < lo;
          best[s - 1] = sw ? hi : lo;
          best[s] = sw ? lo : hi;
        }
      }
    }
#pragma unroll
    for (int s = 0; s < 8; ++s)
      ckey[(size_t)(i0 + t) * 128 + bs * 8 + s] = best[s];
  }
}

// refine v5: v4's group-parallel rank machinery, with the two measured
// pathologies fixed: (1) plain stores (nt defeated write-combining at high
// issue rate -> 4x WRITE_SIZE in r9); (2) occupancy capped at 4 blocks/CU
// via dynamic-LDS pad (r9's ~6 blocks/CU thrashed the gather cache:
// FETCH 50 -> 155 MB).
__global__ __launch_bounds__(256) void refine_gen(
    const float* __restrict__ X, const uint* __restrict__ ckey,
    const float* __restrict__ gaps, const int* __restrict__ nnc,
    float* __restrict__ out) {
  extern __shared__ char dynpad[];    // 29696 B at launch: occupancy cap
  (void)dynpad;
  __shared__ uint keys[4][128];
  __shared__ uint seln[4][16];
  __shared__ uint srank[4][16];       // rank -> neighbor index
  __shared__ float xs[4][512];        // own-row stash (broadcast reads)
  const int w = threadIdx.x >> 6, l = threadIdx.x & 63;
  const int row = blockIdx.x * 4 + w;

  uint k0 = ckey[(size_t)row * 128 + l];
  uint k1 = ckey[(size_t)row * 128 + 64 + l];
  keys[w][l] = k0;
  keys[w][64 + l] = k1;

  // own-row fragment (lane owns floats [8l, 8l+8)) — also stashed to LDS
  const float4* xr = (const float4*)(X + (size_t)row * DD) + l * 2;
  float4 xa = xr[0], xb = xr[1];
  float4* xsp = (float4*)xs[w];
  xsp[l * 2] = xa;
  xsp[l * 2 + 1] = xb;

  __syncthreads();

  // exact rank of each key among the 128 (keys unique by j-bits) -> top-16
  int r0 = 0, r1 = 0;
  const uint4* kk = (const uint4*)keys[w];
#pragma unroll
  for (int i = 0; i < 32; ++i) {
    uint4 v = kk[i];
    r0 += (v.x < k0) + (v.y < k0) + (v.z < k0) + (v.w < k0);
    r1 += (v.x < k1) + (v.y < k1) + (v.z < k1) + (v.w < k1);
  }
  if (r0 < 16) seln[w][r0] = k0 & 8191u;
  if (r1 < 16) seln[w][r1] = k1 & 8191u;
  __syncthreads();

  // group-parallel f32 distance: group g (lanes 4g..4g+3) -> candidate g.
  const int q = l & 3, g = l >> 2;
  const int jg = (int)seln[w][g];
  const float* yrow = X + (size_t)jg * DD;
  const float4* xls = (const float4*)xs[w];
  float a = 0.f;
#pragma unroll
  for (int k = 0; k < 32; ++k) {
    float4 y4 = ((const float4*)yrow)[k * 4 + q];
    float4 x4 = xls[k * 4 + q];
    float d0 = x4.x - y4.x;
    float d1 = x4.y - y4.y;
    float d2 = x4.z - y4.z;
    float d3 = x4.w - y4.w;
    a = fmaf(d0, d0, a);
    a = fmaf(d1, d1, a);
    a = fmaf(d2, d2, a);
    a = fmaf(d3, d3, a);
  }
  // xor-reduce within the 4-lane group: all 4 lanes hold d_g
  a += __shfl_xor(a, 1);
  a += __shfl_xor(a, 2);

  // group-parallel rank: lane q handles opponents u = 4q..4q+3
  int cnt = 0;
#pragma unroll
  for (int uu = 0; uu < 4; ++uu) {
    int u = q * 4 + uu;
    float du = __shfl(a, u * 4, 64);       // group u's sum (lane 4u holds it)
    int ju = (int)seln[w][u];
    cnt += (du < a || (du == a && ju < jg)) ? 1 : 0;  // self-pair adds 0
  }
  cnt += __shfl_xor(cnt, 1);
  cnt += __shfl_xor(cnt, 2);               // cnt = rank of candidate g
  if (q == 0) srank[w][cnt] = (uint)jg;    // ranks are a permutation: no clash
  __syncthreads();

  // targets are ranks 1..4 (rank 0 = self): direct lookup, then gather+interp
  int jsel[4];
  float gv[4];
#pragma unroll
  for (int o = 0; o < 4; ++o) {
    gv[o] = gaps[row * 4 + o];
    int target = nnc[row * 4 + o] + 1;     // skip self (rank 0)
    jsel[o] = (int)srank[w][target];
  }

#pragma unroll
  for (int o = 0; o < 4; ++o) {
    const float4* yr = (const float4*)(X + (size_t)jsel[o] * DD) + l * 2;
    float4 ya = yr[0], yb = yr[1];
    float gp = gv[o];
    f32x4 r0v, r1v;
    r0v.x = fmaf(gp, ya.x - xa.x, xa.x);
    r0v.y = fmaf(gp, ya.y - xa.y, xa.y);
    r0v.z = fmaf(gp, ya.z - xa.z, xa.z);
    r0v.w = fmaf(gp, ya.w - xa.w, xa.w);
    r1v.x = fmaf(gp, yb.x - xb.x, xb.x);
    r1v.y = fmaf(gp, yb.y - xb.y, xb.y);
    r1v.z = fmaf(gp, yb.z - xb.z, xb.z);
    r1v.w = fmaf(gp, yb.w - xb.w, xb.w);
    f32x4* dst = (f32x4*)(out + ((size_t)row * 4 + o) * DD) + l * 2;
    dst[0] = r0v;                          // plain stores: L2 write-combine
    dst[1] = r1v;
  }
}

extern "C" void kernel_launch(void* const* d_in, const int* in_sizes, int n_in,
                              void* d_out, int out_size, void* d_ws, size_t ws_size,
                              hipStream_t stream) {
  const float* X = (const float*)d_in[0];
  const float* gaps = (const float*)d_in[1];
  const int* nnc = (const int*)d_in[2];
  float* out = (float*)d_out;

  int* sqq = (int*)d_ws;                                      // 32 KB
  uint2* Xb8 = (uint2*)((char*)d_ws + 32768);                 // 4 MB i8 X
  uint* ckey = (uint*)((char*)d_ws + 32768 + 4194304);        // 4 MB candidates

  cvtq8_kernel<<<TT / 4, 256, 0, stream>>>(X, Xb8, sqq);
  gemm_topk<<<1024, 256, 0, stream>>>((const char*)Xb8, sqq, ckey);
  // 29696 B dynamic LDS: static 10752 + 29696 = 40448 B/block -> 4 blocks/CU
  refine_gen<<<TT / 4, 256, 29696, stream>>>(X, ckey, gaps, nnc, out);
}